// Round 20
// baseline (101.082 us; speedup 1.0000x reference)
//
#include <hip/hip_runtime.h>
#include <hip/hip_bf16.h>
#include <string.h>

#define NHEAD 12
#define EMB 768
#define HDD 64
#define SEQ 2048

typedef __attribute__((ext_vector_type(4))) float f32x4;
typedef __attribute__((ext_vector_type(8))) short short8;
typedef __attribute__((ext_vector_type(4))) short short4v;
typedef __attribute__((ext_vector_type(2))) unsigned uint2v;
typedef unsigned int u32;

#define GLL16(g, l)                                                            \
    __builtin_amdgcn_global_load_lds(                                          \
        (const __attribute__((address_space(1))) u32*)(g),                     \
        (__attribute__((address_space(3))) u32*)(l), 16, 0, 0)

static __device__ __forceinline__ short bf16s(float f) {
    unsigned u = __builtin_bit_cast(unsigned, f);
    u = (u + 0x7fffu + ((u >> 16) & 1u)) >> 16;
    return (short)u;
}
static __device__ __forceinline__ float bf2f(short s) {
    unsigned u = ((unsigned)(unsigned short)s) << 16;
    return __builtin_bit_cast(float, u);
}
static __device__ __forceinline__ float ex2(float x) {
    float r;
    asm("v_exp_f32 %0, %1" : "=v"(r) : "v"(x));
    return r;
}
static __device__ __forceinline__ unsigned pk2(float a, float b) {
    float2 f2;
    f2.x = a;
    f2.y = b;
    __hip_bfloat162 h = __float22bfloat162_rn(f2);
    unsigned r;
    memcpy(&r, &h, 4);
    return r;
}

// ---- fused converts: one dispatch, block-uniform branch on block range ----
__global__ void k_cvt_all(const float* __restrict__ x, const float* __restrict__ Wq,
                          const float* __restrict__ Wk, const float* __restrict__ Wv,
                          const float* __restrict__ Wo, short* __restrict__ xb,
                          short* __restrict__ WqT, short* __restrict__ WkT,
                          short* __restrict__ WvT, short* __restrict__ WoT) {
    const int bid = blockIdx.x, t = threadIdx.x;
    if (bid < 1536) {
        const int i = (bid * 256 + t) * 8;
        const f32x4* s = (const f32x4*)(x + i);
        f32x4 a = s[0], b = s[1];
        short8 o;
        o[0] = bf16s(a[0]); o[1] = bf16s(a[1]); o[2] = bf16s(a[2]); o[3] = bf16s(a[3]);
        o[4] = bf16s(b[0]); o[5] = bf16s(b[1]); o[6] = bf16s(b[2]); o[7] = bf16s(b[3]);
        *(short8*)(xb + i) = o;
    } else if (bid < 1968) {
        const int idx = bid - 1536;
        const int h = idx % 12, e0 = ((idx / 12) % 12) * 64, z = idx / 144;
        const float* W = z == 0 ? Wq : (z == 1 ? Wk : Wv);
        short* Wt = z == 0 ? WqT : (z == 1 ? WkT : WvT);
        __shared__ float tile[64][65];
        const int r = t >> 2, c0 = (t & 3) * 16;
        const float* src = W + (h * EMB + e0 + r) * HDD + c0;
#pragma unroll
        for (int i = 0; i < 16; ++i) tile[r][c0 + i] = src[i];
        __syncthreads();
        short* dst = Wt + (h * HDD + r) * EMB + e0 + c0;  // r acts as d here
#pragma unroll
        for (int i = 0; i < 16; ++i) dst[i] = bf16s(tile[c0 + i][r]);
    } else {
        const int idx = bid - 1968;
        const int k0 = (idx % 12) * 64, n0 = (idx / 12) * 64;
        __shared__ float tile[64][65];
        const int r = t >> 2, c0 = (t & 3) * 16;
        const float* src = Wo + (k0 + r) * EMB + n0 + c0;
#pragma unroll
        for (int i = 0; i < 16; ++i) tile[r][c0 + i] = src[i];
        __syncthreads();
        short* dst = WoT + (n0 + r) * EMB + k0 + c0;
#pragma unroll
        for (int i = 0; i < 16; ++i) dst[i] = bf16s(tile[c0 + i][r]);
    }
}

// ---- GEMM (r19: m97 structure + BK32 chunk swizzle + single-barrier dbuf) ----
template <int MODE>
__global__ __launch_bounds__(256) void k_gemm(
        const short* __restrict__ xb, const short* __restrict__ Wt0,
        const short* __restrict__ Wt1, const short* __restrict__ Wt2,
        short* __restrict__ Qo, short* __restrict__ Ko, short* __restrict__ Vo,
        const float* __restrict__ bias, float* __restrict__ Fout) {
    __shared__ alignas(16) short As[2][128 * 32];
    __shared__ alignas(16) short Bs[2][128 * 32];
    const int t = threadIdx.x, lane = t & 63, wave = t >> 6;
    const int z = (MODE == 0) ? blockIdx.z : 0;
    const short* Ap;
    const short* Bp;
    int m0, n0;
    if (MODE == 1) {
        Ap = xb; Bp = Wt0; m0 = blockIdx.y * 128; n0 = blockIdx.x * 128;
    } else if (z == 0) {
        Ap = xb; Bp = Wt0; m0 = blockIdx.y * 128; n0 = blockIdx.x * 128;
    } else if (z == 1) {
        Ap = xb; Bp = Wt1; m0 = blockIdx.y * 128; n0 = blockIdx.x * 128;
    } else {  // V^T: A = WvT (768 rows), B = xb (4096 rows)
        Ap = Wt2; Bp = xb; m0 = blockIdx.x * 128; n0 = blockIdx.y * 128;
    }

    const int srow = lane >> 2;
    const int scolSw = ((lane & 3) ^ ((srow >> 1) & 3)) * 8;
    const short* gA = Ap + (long)(m0 + wave * 32 + srow) * EMB + scolSw;
    const short* gB = Bp + (long)(n0 + wave * 32 + srow) * EMB + scolSw;
    const int ldoff = (wave * 32) * 32;

    const int wm = (wave >> 1) * 64, wn = (wave & 1) * 64;
    const int fr = lane & 15, hi = lane >> 4;
    const int rdoff = (hi ^ ((fr >> 1) & 3)) * 8;

    f32x4 acc[4][4];
#pragma unroll
    for (int i = 0; i < 4; ++i)
#pragma unroll
        for (int j = 0; j < 4; ++j)
#pragma unroll
            for (int e = 0; e < 4; ++e) acc[i][j][e] = 0.f;

    GLL16(gA, &As[0][ldoff]);
    GLL16(gA + 16 * EMB, &As[0][ldoff + 16 * 32]);
    GLL16(gB, &Bs[0][ldoff]);
    GLL16(gB + 16 * EMB, &Bs[0][ldoff + 16 * 32]);
    __syncthreads();

    int cur = 0;
    for (int kk = 0; kk < EMB; kk += 32) {
        const int nxt = cur ^ 1;
        if (kk + 32 < EMB) {
            GLL16(gA + kk + 32, &As[nxt][ldoff]);
            GLL16(gA + kk + 32 + 16 * EMB, &As[nxt][ldoff + 16 * 32]);
            GLL16(gB + kk + 32, &Bs[nxt][ldoff]);
            GLL16(gB + kk + 32 + 16 * EMB, &Bs[nxt][ldoff + 16 * 32]);
        }
        const short* curA = &As[cur][0];
        const short* curB = &Bs[cur][0];
        short8 af[4], bfq[4];
#pragma unroll
        for (int i = 0; i < 4; ++i)
            af[i] = *(const short8*)(curA + (wm + i * 16 + fr) * 32 + rdoff);
#pragma unroll
        for (int j = 0; j < 4; ++j)
            bfq[j] = *(const short8*)(curB + (wn + j * 16 + fr) * 32 + rdoff);
#pragma unroll
        for (int i = 0; i < 4; ++i)
#pragma unroll
            for (int j = 0; j < 4; ++j)
                acc[i][j] = __builtin_amdgcn_mfma_f32_16x16x32_bf16(af[i], bfq[j], acc[i][j], 0, 0, 0);
        __syncthreads();
        cur = nxt;
    }

    const int r0 = hi * 4;
#pragma unroll
    for (int i = 0; i < 4; ++i) {
#pragma unroll
        for (int j = 0; j < 4; ++j) {
            const int nbase = n0 + wn + j * 16 + fr;
            float bj = 0.f;
            if (MODE == 1) bj = bias[nbase];
#pragma unroll
            for (int r = 0; r < 4; ++r) {
                const int m = m0 + wm + i * 16 + r0 + r;
                float v = acc[i][j][r];
                if (MODE == 0) {
                    if (z == 2) {
                        const int hh = m >> 6, dd = m & 63;
                        const int bb = nbase >> 11, ss = nbase & 2047;
                        Vo[(long)((bb * NHEAD + hh) * HDD + dd) * SEQ + ss] = bf16s(v);
                    } else {
                        const int bb = m >> 11, ss = m & 2047;
                        const int hh = nbase >> 6, dd = nbase & 63;
                        short* Dst = (z == 0) ? Qo : Ko;
                        if (z == 0) v *= 0.18033688f;  // 0.125 * log2(e): exp2-space
                        Dst[(long)((bb * NHEAD + hh) * SEQ + ss) * HDD + dd] = bf16s(v);
                    }
                } else {
                    Fout[(long)m * EMB + nbase] = v + bj;
                }
            }
        }
    }
}

// ---- causal flash attention: QBLK=128 (2 q-subtiles/wave, r6-proven) +
// SPLIT-K (r15-proven) + exp2/cvt_pk softmax (r17-proven).
// 128-row strips 0..15 per (b,h); strips 8..15 split at tile 16.
// Per tile: kf read once for both qi, V-frags read once feeding both qi's PV
// (both P's in registers; per-wave LDS P region reused sequentially).
// No fully-masked qi can occur: k0≡0 mod 64, qbase≡0 mod 16 and the
// k0<=wq+31 guard make the fully-masked window unreachable (r6 analysis).
__global__ __launch_bounds__(256) void k_attn(
        const short* __restrict__ Q, const short* __restrict__ K,
        const short* __restrict__ VT, short* __restrict__ O,
        short* __restrict__ Ub, float* __restrict__ Mb, float* __restrict__ Lb) {
    __shared__ alignas(16) short Kbuf[2][64 * 72];   // [key][d]; reused as O buf
    __shared__ alignas(16) short Vbuf[2][64 * 72];   // [d][key]
    __shared__ alignas(16) short Ps[4][16 * 72];     // per-wave P scratch
    const int bh = blockIdx.x;
    const int h = bh % NHEAD, b = bh / NHEAD;
    const int yy = blockIdx.y;
    int strip, kb, ke, chunk, split;
    if (yy < 8)       { strip = 8 + yy;  kb = 0;  ke = 16;          chunk = 0; split = 1; }
    else if (yy < 16) { strip = 23 - yy; kb = 16; ke = 2 * strip + 2; chunk = 1; split = 1; }
    else              { strip = 23 - yy; kb = 0;  ke = 2 * strip + 2; chunk = 0; split = 0; }
    const int q0 = strip * 128;
    const int t = threadIdx.x, lane = t & 63, wave = t >> 6;
    const long base = (long)(b * NHEAD + h) * SEQ * HDD;
    const short* Qg = Q + base;
    const short* Kg = K + base;
    const short* Vg = VT + base;  // [64][2048]
    const int fr = lane & 15, hi = lane >> 4, fk = hi * 8, r0 = hi * 4;
    const int wq = q0 + wave * 32;  // this wave's 32 q-rows (2 subtiles of 16)

    short8 qf[2][2];
#pragma unroll
    for (int qi = 0; qi < 2; ++qi)
#pragma unroll
        for (int c = 0; c < 2; ++c)
            qf[qi][c] = *(const short8*)(Qg + (long)(wq + qi * 16 + fr) * HDD + c * 32 + fk);

    f32x4 oacc[2][4];  // per qi: O^T rows d = dt*16+r0+r, col q = fr
#pragma unroll
    for (int qi = 0; qi < 2; ++qi)
#pragma unroll
        for (int i = 0; i < 4; ++i)
#pragma unroll
            for (int e = 0; e < 4; ++e) oacc[qi][i][e] = 0.f;
    float mrun[2] = {-3e38f, -3e38f}, lrun[2] = {0.f, 0.f};

    // staging: 256 threads, two short8 each for K and V per tile
    const int srow = t >> 2, sc = (t & 3) * 16;
    const short* KgS = Kg + (long)srow * HDD + sc;
    const short* VgS = Vg + (long)srow * SEQ + sc;
    short* Pw = &Ps[wave][0];

    // prologue: tile kb -> buf0; prefetch tile kb+1 into regs
    short8 kv0 = *(const short8*)(KgS + (long)(kb * 64) * HDD);
    short8 kv1 = *(const short8*)(KgS + (long)(kb * 64) * HDD + 8);
    short8 vv0 = *(const short8*)(VgS + kb * 64);
    short8 vv1 = *(const short8*)(VgS + kb * 64 + 8);
    *(short8*)(&Kbuf[0][srow * 72 + sc]) = kv0;
    *(short8*)(&Kbuf[0][srow * 72 + sc + 8]) = kv1;
    *(short8*)(&Vbuf[0][srow * 72 + sc]) = vv0;
    *(short8*)(&Vbuf[0][srow * 72 + sc + 8]) = vv1;
    if (ke - kb > 1) {
        kv0 = *(const short8*)(KgS + (long)(kb * 64 + 64) * HDD);
        kv1 = *(const short8*)(KgS + (long)(kb * 64 + 64) * HDD + 8);
        vv0 = *(const short8*)(VgS + kb * 64 + 64);
        vv1 = *(const short8*)(VgS + kb * 64 + 64 + 8);
    }
    __syncthreads();

    for (int kt = kb; kt < ke; ++kt) {
        const int k0 = kt * 64;
        const int cur = (kt - kb) & 1;
        if (kt + 1 < ke) {
            *(short8*)(&Kbuf[cur ^ 1][srow * 72 + sc]) = kv0;
            *(short8*)(&Kbuf[cur ^ 1][srow * 72 + sc + 8]) = kv1;
            *(short8*)(&Vbuf[cur ^ 1][srow * 72 + sc]) = vv0;
            *(short8*)(&Vbuf[cur ^ 1][srow * 72 + sc + 8]) = vv1;
            if (kt + 2 < ke) {  // issue tile kt+2 loads early
                kv0 = *(const short8*)(KgS + (long)(k0 + 128) * HDD);
                kv1 = *(const short8*)(KgS + (long)(k0 + 128) * HDD + 8);
                vv0 = *(const short8*)(VgS + (k0 + 128));
                vv1 = *(const short8*)(VgS + (k0 + 128) + 8);
            }
        }
        if (k0 <= wq + 31) {  // wave-uniform activity guard (32 q-rows)
            const short* Ks = &Kbuf[cur][0];
            const short* Vs = &Vbuf[cur][0];

            // K fragments: read ONCE, shared by both qi
            short8 kf[4][2];
#pragma unroll
            for (int nt = 0; nt < 4; ++nt) {
                kf[nt][0] = *(const short8*)(Ks + (nt * 16 + fr) * 72 + fk);
                kf[nt][1] = *(const short8*)(Ks + (nt * 16 + fr) * 72 + 32 + fk);
            }

            short8 pfq[2][2];  // packed P B-frags for both qi
#pragma unroll
            for (int qi = 0; qi < 2; ++qi) {
                const int qbase = wq + qi * 16;
                f32x4 st[4];
#pragma unroll
                for (int nt = 0; nt < 4; ++nt) {
#pragma unroll
                    for (int e = 0; e < 4; ++e) st[nt][e] = 0.f;
                    st[nt] = __builtin_amdgcn_mfma_f32_16x16x32_bf16(kf[nt][0], qf[qi][0], st[nt], 0, 0, 0);
                    st[nt] = __builtin_amdgcn_mfma_f32_16x16x32_bf16(kf[nt][1], qf[qi][1], st[nt], 0, 0, 0);
                }

                float p[4][4];
                float pmax = -3e38f;
                if (k0 + 63 > qbase) {  // diagonal-overlap: causal mask
                    const int myq = qbase + fr;
#pragma unroll
                    for (int nt = 0; nt < 4; ++nt)
#pragma unroll
                        for (int r = 0; r < 4; ++r) {
                            float s = st[nt][r];
                            if (k0 + nt * 16 + r0 + r > myq) s = -3e38f;
                            p[nt][r] = s;
                            pmax = fmaxf(pmax, s);
                        }
                } else {
#pragma unroll
                    for (int nt = 0; nt < 4; ++nt)
#pragma unroll
                        for (int r = 0; r < 4; ++r) {
                            p[nt][r] = st[nt][r];
                            pmax = fmaxf(pmax, st[nt][r]);
                        }
                }
                pmax = fmaxf(pmax, __shfl_xor(pmax, 16, 64));
                pmax = fmaxf(pmax, __shfl_xor(pmax, 32, 64));
                const float mnew = fmaxf(mrun[qi], pmax);
                const float corr = ex2(mrun[qi] - mnew);  // log2-space rescale
                mrun[qi] = mnew;
                float rsum = 0.f;
#pragma unroll
                for (int nt = 0; nt < 4; ++nt)
#pragma unroll
                    for (int r = 0; r < 4; ++r) {
                        const float e = ex2(p[nt][r] - mnew);
                        p[nt][r] = e;
                        rsum += e;
                    }
                rsum += __shfl_xor(rsum, 16, 64);
                rsum += __shfl_xor(rsum, 32, 64);
                lrun[qi] = lrun[qi] * corr + rsum;
#pragma unroll
                for (int dt = 0; dt < 4; ++dt)
#pragma unroll
                    for (int e = 0; e < 4; ++e) oacc[qi][dt][e] *= corr;

                // P -> per-wave LDS scratch (reused per qi), read back as B-frag
#pragma unroll
                for (int nt = 0; nt < 4; ++nt) {
                    uint2v w;
                    w[0] = pk2(p[nt][0], p[nt][1]);
                    w[1] = pk2(p[nt][2], p[nt][3]);
                    *(uint2v*)(Pw + fr * 72 + nt * 16 + r0) = w;
                }
                pfq[qi][0] = *(const short8*)(Pw + fr * 72 + fk);
                pfq[qi][1] = *(const short8*)(Pw + fr * 72 + 32 + fk);
            }

            // PV: V fragments read ONCE, feed both qi
#pragma unroll
            for (int kc = 0; kc < 2; ++kc) {
#pragma unroll
                for (int dt = 0; dt < 4; ++dt) {
                    const short8 vf = *(const short8*)(Vs + (dt * 16 + fr) * 72 + kc * 32 + fk);
                    oacc[0][dt] = __builtin_amdgcn_mfma_f32_16x16x32_bf16(vf, pfq[0][kc], oacc[0][dt], 0, 0, 0);
                    oacc[1][dt] = __builtin_amdgcn_mfma_f32_16x16x32_bf16(vf, pfq[1][kc], oacc[1][dt], 0, 0, 0);
                }
            }
        }
        __syncthreads();  // buf[cur^1] writes visible; buf[cur] reads done
    }

    if (split) {
        // partial epilogue: U^T bf16 [64 d][128 q] + per-row m,l (f32)
        const int pidx = (bh * 8 + (strip - 8)) * 2 + chunk;
        short* Up = Ub + pidx * 8192;
#pragma unroll
        for (int qi = 0; qi < 2; ++qi)
#pragma unroll
            for (int dt = 0; dt < 4; ++dt)
#pragma unroll
                for (int r = 0; r < 4; ++r)
                    Up[(dt * 16 + r0 + r) * 128 + wave * 32 + qi * 16 + fr] = bf16s(oacc[qi][dt][r]);
        if (lane < 16) {
#pragma unroll
            for (int qi = 0; qi < 2; ++qi) {
                Mb[pidx * 128 + wave * 32 + qi * 16 + lane] = mrun[qi];
                Lb[pidx * 128 + wave * 32 + qi * 16 + lane] = lrun[qi];
            }
        }
        return;
    }

    // direct epilogue: transpose O^T via LDS (Kbuf reused: 128*72*2B fits) and store
    short* Os = &Kbuf[0][0];
#pragma unroll
    for (int qi = 0; qi < 2; ++qi) {
        const float iv = 1.0f / lrun[qi];
#pragma unroll
        for (int dt = 0; dt < 4; ++dt) {
            uint2v w;
            w[0] = pk2(oacc[qi][dt][0] * iv, oacc[qi][dt][1] * iv);
            w[1] = pk2(oacc[qi][dt][2] * iv, oacc[qi][dt][3] * iv);
            *(uint2v*)(Os + (wave * 32 + qi * 16 + fr) * 72 + dt * 16 + r0) = w;
        }
    }
    __syncthreads();
    {
        // 2 threads/row, 32 cols each => FOUR short8 stores (r3 lesson)
        const int row = t >> 1, half = t & 1;
        const short8 o0 = *(const short8*)(Os + row * 72 + half * 32);
        const short8 o1 = *(const short8*)(Os + row * 72 + half * 32 + 8);
        const short8 o2 = *(const short8*)(Os + row * 72 + half * 32 + 16);
        const short8 o3 = *(const short8*)(Os + row * 72 + half * 32 + 24);
        short* Og = O + (long)(b * SEQ + q0 + row) * EMB + h * HDD + half * 32;
        *(short8*)Og = o0;
        *(short8*)(Og + 8) = o1;
        *(short8*)(Og + 16) = o2;
        *(short8*)(Og + 24) = o3;
    }
}

// ---- split-K merge, 128 q-rows per block (strips 8..15) ----
__global__ __launch_bounds__(256) void k_merge(
        const short* __restrict__ Ub, const float* __restrict__ Mb,
        const float* __restrict__ Lb, short* __restrict__ O) {
    __shared__ float aS[128], bS[128], iL[128];
    __shared__ short tile[128 * 72];
    const int bid = blockIdx.x;
    const int bh = bid >> 3, sidx = bid & 7;
    const int h = bh % NHEAD, b = bh / NHEAD;
    const int q0 = (8 + sidx) * 128;
    const int p0 = (bh * 8 + sidx) * 2, p1 = p0 + 1;
    const int t = threadIdx.x;
    if (t < 128) {
        const float m1 = Mb[p0 * 128 + t], m2 = Mb[p1 * 128 + t];
        const float l1 = Lb[p0 * 128 + t], l2 = Lb[p1 * 128 + t];
        const float m = fmaxf(m1, m2);
        const float a = ex2(m1 - m), bb = ex2(m2 - m);
        aS[t] = a;
        bS[t] = bb;
        iL[t] = 1.0f / (l1 * a + l2 * bb);
    }
    __syncthreads();
    {
        const int d = t >> 2, qg = (t & 3) * 32;
#pragma unroll
        for (int j = 0; j < 4; ++j) {
            const short8 u1 = *(const short8*)(Ub + p0 * 8192 + d * 128 + qg + j * 8);
            const short8 u2 = *(const short8*)(Ub + p1 * 8192 + d * 128 + qg + j * 8);
#pragma unroll
            for (int i = 0; i < 8; ++i) {
                const int q = qg + j * 8 + i;
                tile[q * 72 + d] = bf16s((bf2f(u1[i]) * aS[q] + bf2f(u2[i]) * bS[q]) * iL[q]);
            }
        }
    }
    __syncthreads();
    {
        const int row = t >> 1, half = t & 1;
        const short8 o0 = *(const short8*)(tile + row * 72 + half * 32);
        const short8 o1 = *(const short8*)(tile + row * 72 + half * 32 + 8);
        const short8 o2 = *(const short8*)(tile + row * 72 + half * 32 + 16);
        const short8 o3 = *(const short8*)(tile + row * 72 + half * 32 + 24);
        short* Og = O + (long)(b * SEQ + q0 + row) * EMB + h * HDD + half * 32;
        *(short8*)Og = o0;
        *(short8*)(Og + 8) = o1;
        *(short8*)(Og + 16) = o2;
        *(short8*)(Og + 24) = o3;
    }
}

extern "C" void kernel_launch(void* const* d_in, const int* in_sizes, int n_in,
                              void* d_out, int out_size, void* d_ws, size_t ws_size,
                              hipStream_t stream) {
    const float* x  = (const float*)d_in[0];
    const float* Wq = (const float*)d_in[1];
    const float* Wk = (const float*)d_in[2];
    const float* Wv = (const float*)d_in[3];
    const float* Wo = (const float*)d_in[4];
    const float* bo = (const float*)d_in[5];
    float* out = (float*)d_out;

    char* ws = (char*)d_ws;
    short* xb  = (short*)(ws + 0);         // 4096x768 bf16 (dead after gemm0)
    short* WqT = (short*)(ws + 6291456);   // (dead after gemm0)
    short* WkT = (short*)(ws + 7471104);
    short* WvT = (short*)(ws + 8650752);
    short* WoT = (short*)(ws + 9830400);
    short* Qb  = (short*)(ws + 11010048);  // [2,12,2048,64] bf16 (pre-scaled, log2-space)
    short* Kb  = (short*)(ws + 17301504);  // [2,12,2048,64]
    short* VTb = (short*)(ws + 23592960);  // [2,12,64,2048] (transposed)
    short* Ob  = (short*)(ws + 29884416);  // [4096,768] bf16
    // split-K partials overlay the dead xb/WqT regions during attn+merge:
    short* Ub  = (short*)(ws + 0);         // 384 x [64][128] bf16 = 6,291,456 B
    float* Mb  = (float*)(ws + 6291456);   // 384 x 128 f32 = 196,608 B
    float* Lb  = (float*)(ws + 6488064);   // 384 x 128 f32 = 196,608 B

    k_cvt_all<<<dim3(2112), dim3(256), 0, stream>>>(
        x, Wq, Wk, Wv, Wo, xb, WqT, WkT, WvT, WoT);
    k_gemm<0><<<dim3(6, 32, 3), dim3(256), 0, stream>>>(
        xb, WqT, WkT, WvT, Qb, Kb, VTb, (const float*)nullptr, (float*)nullptr);
    k_attn<<<dim3(24, 24), dim3(256), 0, stream>>>(Qb, Kb, VTb, Ob, Ub, Mb, Lb);
    k_merge<<<dim3(192), dim3(256), 0, stream>>>(Ub, Mb, Lb, Ob);
    k_gemm<1><<<dim3(6, 32, 1), dim3(256), 0, stream>>>(
        Ob, WoT, (const short*)nullptr, (const short*)nullptr,
        (short*)nullptr, (short*)nullptr, (short*)nullptr, bo, out);
}

// Round 21
// 95.062 us; speedup vs baseline: 1.0633x; 1.0633x over previous
//
#include <hip/hip_runtime.h>
#include <hip/hip_bf16.h>
#include <string.h>

#define NHEAD 12
#define EMB 768
#define HDD 64
#define SEQ 2048

typedef __attribute__((ext_vector_type(4))) float f32x4;
typedef __attribute__((ext_vector_type(8))) short short8;
typedef __attribute__((ext_vector_type(4))) short short4v;
typedef __attribute__((ext_vector_type(2))) unsigned uint2v;
typedef unsigned int u32;

#define GLL16(g, l)                                                            \
    __builtin_amdgcn_global_load_lds(                                          \
        (const __attribute__((address_space(1))) u32*)(g),                     \
        (__attribute__((address_space(3))) u32*)(l), 16, 0, 0)

static __device__ __forceinline__ short bf16s(float f) {
    unsigned u = __builtin_bit_cast(unsigned, f);
    u = (u + 0x7fffu + ((u >> 16) & 1u)) >> 16;
    return (short)u;
}
static __device__ __forceinline__ float bf2f(short s) {
    unsigned u = ((unsigned)(unsigned short)s) << 16;
    return __builtin_bit_cast(float, u);
}
static __device__ __forceinline__ float ex2(float x) {
    float r;
    asm("v_exp_f32 %0, %1" : "=v"(r) : "v"(x));
    return r;
}
static __device__ __forceinline__ unsigned pk2(float a, float b) {
    float2 f2;
    f2.x = a;
    f2.y = b;
    __hip_bfloat162 h = __float22bfloat162_rn(f2);
    unsigned r;
    memcpy(&r, &h, 4);
    return r;
}

// ---- fused converts: one dispatch, block-uniform branch on block range ----
__global__ void k_cvt_all(const float* __restrict__ x, const float* __restrict__ Wq,
                          const float* __restrict__ Wk, const float* __restrict__ Wv,
                          const float* __restrict__ Wo, short* __restrict__ xb,
                          short* __restrict__ WqT, short* __restrict__ WkT,
                          short* __restrict__ WvT, short* __restrict__ WoT) {
    const int bid = blockIdx.x, t = threadIdx.x;
    if (bid < 1536) {
        const int i = (bid * 256 + t) * 8;
        const f32x4* s = (const f32x4*)(x + i);
        f32x4 a = s[0], b = s[1];
        short8 o;
        o[0] = bf16s(a[0]); o[1] = bf16s(a[1]); o[2] = bf16s(a[2]); o[3] = bf16s(a[3]);
        o[4] = bf16s(b[0]); o[5] = bf16s(b[1]); o[6] = bf16s(b[2]); o[7] = bf16s(b[3]);
        *(short8*)(xb + i) = o;
    } else if (bid < 1968) {
        const int idx = bid - 1536;
        const int h = idx % 12, e0 = ((idx / 12) % 12) * 64, z = idx / 144;
        const float* W = z == 0 ? Wq : (z == 1 ? Wk : Wv);
        short* Wt = z == 0 ? WqT : (z == 1 ? WkT : WvT);
        __shared__ float tile[64][65];
        const int r = t >> 2, c0 = (t & 3) * 16;
        const float* src = W + (h * EMB + e0 + r) * HDD + c0;
#pragma unroll
        for (int i = 0; i < 16; ++i) tile[r][c0 + i] = src[i];
        __syncthreads();
        short* dst = Wt + (h * HDD + r) * EMB + e0 + c0;  // r acts as d here
#pragma unroll
        for (int i = 0; i < 16; ++i) dst[i] = bf16s(tile[c0 + i][r]);
    } else {
        const int idx = bid - 1968;
        const int k0 = (idx % 12) * 64, n0 = (idx / 12) * 64;
        __shared__ float tile[64][65];
        const int r = t >> 2, c0 = (t & 3) * 16;
        const float* src = Wo + (k0 + r) * EMB + n0 + c0;
#pragma unroll
        for (int i = 0; i < 16; ++i) tile[r][c0 + i] = src[i];
        __syncthreads();
        short* dst = WoT + (n0 + r) * EMB + k0 + c0;
#pragma unroll
        for (int i = 0; i < 16; ++i) dst[i] = bf16s(tile[c0 + i][r]);
    }
}

// ---- GEMM (r19: m97 structure + BK32 chunk swizzle + single-barrier dbuf) ----
template <int MODE>
__global__ __launch_bounds__(256) void k_gemm(
        const short* __restrict__ xb, const short* __restrict__ Wt0,
        const short* __restrict__ Wt1, const short* __restrict__ Wt2,
        short* __restrict__ Qo, short* __restrict__ Ko, short* __restrict__ Vo,
        const float* __restrict__ bias, float* __restrict__ Fout) {
    __shared__ alignas(16) short As[2][128 * 32];
    __shared__ alignas(16) short Bs[2][128 * 32];
    const int t = threadIdx.x, lane = t & 63, wave = t >> 6;
    const int z = (MODE == 0) ? blockIdx.z : 0;
    const short* Ap;
    const short* Bp;
    int m0, n0;
    if (MODE == 1) {
        Ap = xb; Bp = Wt0; m0 = blockIdx.y * 128; n0 = blockIdx.x * 128;
    } else if (z == 0) {
        Ap = xb; Bp = Wt0; m0 = blockIdx.y * 128; n0 = blockIdx.x * 128;
    } else if (z == 1) {
        Ap = xb; Bp = Wt1; m0 = blockIdx.y * 128; n0 = blockIdx.x * 128;
    } else {  // V^T: A = WvT (768 rows), B = xb (4096 rows)
        Ap = Wt2; Bp = xb; m0 = blockIdx.x * 128; n0 = blockIdx.y * 128;
    }

    const int srow = lane >> 2;
    const int scolSw = ((lane & 3) ^ ((srow >> 1) & 3)) * 8;
    const short* gA = Ap + (long)(m0 + wave * 32 + srow) * EMB + scolSw;
    const short* gB = Bp + (long)(n0 + wave * 32 + srow) * EMB + scolSw;
    const int ldoff = (wave * 32) * 32;

    const int wm = (wave >> 1) * 64, wn = (wave & 1) * 64;
    const int fr = lane & 15, hi = lane >> 4;
    const int rdoff = (hi ^ ((fr >> 1) & 3)) * 8;

    f32x4 acc[4][4];
#pragma unroll
    for (int i = 0; i < 4; ++i)
#pragma unroll
        for (int j = 0; j < 4; ++j)
#pragma unroll
            for (int e = 0; e < 4; ++e) acc[i][j][e] = 0.f;

    GLL16(gA, &As[0][ldoff]);
    GLL16(gA + 16 * EMB, &As[0][ldoff + 16 * 32]);
    GLL16(gB, &Bs[0][ldoff]);
    GLL16(gB + 16 * EMB, &Bs[0][ldoff + 16 * 32]);
    __syncthreads();

    int cur = 0;
    for (int kk = 0; kk < EMB; kk += 32) {
        const int nxt = cur ^ 1;
        if (kk + 32 < EMB) {
            GLL16(gA + kk + 32, &As[nxt][ldoff]);
            GLL16(gA + kk + 32 + 16 * EMB, &As[nxt][ldoff + 16 * 32]);
            GLL16(gB + kk + 32, &Bs[nxt][ldoff]);
            GLL16(gB + kk + 32 + 16 * EMB, &Bs[nxt][ldoff + 16 * 32]);
        }
        const short* curA = &As[cur][0];
        const short* curB = &Bs[cur][0];
        short8 af[4], bfq[4];
#pragma unroll
        for (int i = 0; i < 4; ++i)
            af[i] = *(const short8*)(curA + (wm + i * 16 + fr) * 32 + rdoff);
#pragma unroll
        for (int j = 0; j < 4; ++j)
            bfq[j] = *(const short8*)(curB + (wn + j * 16 + fr) * 32 + rdoff);
#pragma unroll
        for (int i = 0; i < 4; ++i)
#pragma unroll
            for (int j = 0; j < 4; ++j)
                acc[i][j] = __builtin_amdgcn_mfma_f32_16x16x32_bf16(af[i], bfq[j], acc[i][j], 0, 0, 0);
        __syncthreads();
        cur = nxt;
    }

    const int r0 = hi * 4;
#pragma unroll
    for (int i = 0; i < 4; ++i) {
#pragma unroll
        for (int j = 0; j < 4; ++j) {
            const int nbase = n0 + wn + j * 16 + fr;
            float bj = 0.f;
            if (MODE == 1) bj = bias[nbase];
#pragma unroll
            for (int r = 0; r < 4; ++r) {
                const int m = m0 + wm + i * 16 + r0 + r;
                float v = acc[i][j][r];
                if (MODE == 0) {
                    if (z == 2) {
                        const int hh = m >> 6, dd = m & 63;
                        const int bb = nbase >> 11, ss = nbase & 2047;
                        Vo[(long)((bb * NHEAD + hh) * HDD + dd) * SEQ + ss] = bf16s(v);
                    } else {
                        const int bb = m >> 11, ss = m & 2047;
                        const int hh = nbase >> 6, dd = nbase & 63;
                        short* Dst = (z == 0) ? Qo : Ko;
                        if (z == 0) v *= 0.18033688f;  // 0.125 * log2(e): exp2-space
                        Dst[(long)((bb * NHEAD + hh) * SEQ + ss) * HDD + dd] = bf16s(v);
                    }
                } else {
                    Fout[(long)m * EMB + nbase] = v + bj;
                }
            }
        }
    }
}

// ---- causal flash attention with SPLIT-K (r19-proven) + T5 setprio A/B ----
// Only change vs r19: s_setprio(1) around the QK and PV MFMA clusters.
// Mechanism: 3-4 co-resident blocks per CU at independent phases -> scheduler
// can favor MFMA-issuing waves (m191's +4-7% attn case; m190's GEMM null was
// single-block lockstep). Bounded-risk A/B: revert if null/regress.
__global__ __launch_bounds__(256) void k_attn(
        const short* __restrict__ Q, const short* __restrict__ K,
        const short* __restrict__ VT, short* __restrict__ O,
        short* __restrict__ Ub, float* __restrict__ Mb, float* __restrict__ Lb) {
    __shared__ alignas(16) short Kbuf[2][64 * 72];   // [key][d]
    __shared__ alignas(16) short Vbuf[2][64 * 72];   // [d][key]
    __shared__ alignas(16) short Ps[4][16 * 72];     // per-wave P; reused as O buf
    const int bh = blockIdx.x;
    const int h = bh % NHEAD, b = bh / NHEAD;
    const int yy = blockIdx.y;
    int qs, kb, ke, chunk, split;
    if (yy < 16)      { qs = 16 + yy; kb = 0;  ke = 16;     chunk = 0; split = 1; }
    else if (yy < 32) { qs = yy;      kb = 16; ke = qs + 1; chunk = 1; split = 1; }
    else              { qs = 47 - yy; kb = 0;  ke = qs + 1; chunk = 0; split = 0; }
    const int q0 = qs * 64;
    const int t = threadIdx.x, lane = t & 63, wave = t >> 6;
    const long base = (long)(b * NHEAD + h) * SEQ * HDD;
    const short* Qg = Q + base;
    const short* Kg = K + base;
    const short* Vg = VT + base;  // [64][2048]
    const int fr = lane & 15, hi = lane >> 4, fk = hi * 8, r0 = hi * 4;
    const int wq = q0 + wave * 16;  // this wave's 16 q-rows

    short8 qf[2];
#pragma unroll
    for (int c = 0; c < 2; ++c)
        qf[c] = *(const short8*)(Qg + (long)(wq + fr) * HDD + c * 32 + fk);

    f32x4 oacc[4];  // O^T (unnormalized U^T): row d = dt*16+r0+r, col q = fr
#pragma unroll
    for (int i = 0; i < 4; ++i)
#pragma unroll
        for (int e = 0; e < 4; ++e) oacc[i][e] = 0.f;
    float mrun = -3e38f, lrun = 0.f;

    // staging: 256 threads, two short8 each for K and V per tile
    const int srow = t >> 2, sc = (t & 3) * 16;
    const short* KgS = Kg + (long)srow * HDD + sc;
    const short* VgS = Vg + (long)srow * SEQ + sc;
    short* Pw = &Ps[wave][0];

    // prologue: tile kb -> buf0; prefetch tile kb+1 into regs
    short8 kv0 = *(const short8*)(KgS + (long)(kb * 64) * HDD);
    short8 kv1 = *(const short8*)(KgS + (long)(kb * 64) * HDD + 8);
    short8 vv0 = *(const short8*)(VgS + kb * 64);
    short8 vv1 = *(const short8*)(VgS + kb * 64 + 8);
    *(short8*)(&Kbuf[0][srow * 72 + sc]) = kv0;
    *(short8*)(&Kbuf[0][srow * 72 + sc + 8]) = kv1;
    *(short8*)(&Vbuf[0][srow * 72 + sc]) = vv0;
    *(short8*)(&Vbuf[0][srow * 72 + sc + 8]) = vv1;
    if (ke - kb > 1) {
        kv0 = *(const short8*)(KgS + (long)(kb * 64 + 64) * HDD);
        kv1 = *(const short8*)(KgS + (long)(kb * 64 + 64) * HDD + 8);
        vv0 = *(const short8*)(VgS + kb * 64 + 64);
        vv1 = *(const short8*)(VgS + kb * 64 + 64 + 8);
    }
    __syncthreads();

    for (int kt = kb; kt < ke; ++kt) {
        const int k0 = kt * 64;
        const int cur = (kt - kb) & 1;
        if (kt + 1 < ke) {
            *(short8*)(&Kbuf[cur ^ 1][srow * 72 + sc]) = kv0;
            *(short8*)(&Kbuf[cur ^ 1][srow * 72 + sc + 8]) = kv1;
            *(short8*)(&Vbuf[cur ^ 1][srow * 72 + sc]) = vv0;
            *(short8*)(&Vbuf[cur ^ 1][srow * 72 + sc + 8]) = vv1;
            if (kt + 2 < ke) {  // issue tile kt+2 loads early
                kv0 = *(const short8*)(KgS + (long)(k0 + 128) * HDD);
                kv1 = *(const short8*)(KgS + (long)(k0 + 128) * HDD + 8);
                vv0 = *(const short8*)(VgS + (k0 + 128));
                vv1 = *(const short8*)(VgS + (k0 + 128) + 8);
            }
        }
        if (k0 <= wq + 15) {  // wave-uniform activity guard
            const short* Ks = &Kbuf[cur][0];
            const short* Vs = &Vbuf[cur][0];

            f32x4 st[4];
            __builtin_amdgcn_s_setprio(1);
#pragma unroll
            for (int nt = 0; nt < 4; ++nt) {
                const short8 kf0 = *(const short8*)(Ks + (nt * 16 + fr) * 72 + fk);
                const short8 kf1 = *(const short8*)(Ks + (nt * 16 + fr) * 72 + 32 + fk);
#pragma unroll
                for (int e = 0; e < 4; ++e) st[nt][e] = 0.f;
                st[nt] = __builtin_amdgcn_mfma_f32_16x16x32_bf16(kf0, qf[0], st[nt], 0, 0, 0);
                st[nt] = __builtin_amdgcn_mfma_f32_16x16x32_bf16(kf1, qf[1], st[nt], 0, 0, 0);
            }
            __builtin_amdgcn_s_setprio(0);

            float p[4][4];
            float pmax = -3e38f;
            if (k0 + 63 > wq) {  // diagonal-overlap tile: causal mask
                const int myq = wq + fr;
#pragma unroll
                for (int nt = 0; nt < 4; ++nt)
#pragma unroll
                    for (int r = 0; r < 4; ++r) {
                        float s = st[nt][r];
                        if (k0 + nt * 16 + r0 + r > myq) s = -3e38f;
                        p[nt][r] = s;
                        pmax = fmaxf(pmax, s);
                    }
            } else {
#pragma unroll
                for (int nt = 0; nt < 4; ++nt)
#pragma unroll
                    for (int r = 0; r < 4; ++r) {
                        p[nt][r] = st[nt][r];
                        pmax = fmaxf(pmax, st[nt][r]);
                    }
            }
            pmax = fmaxf(pmax, __shfl_xor(pmax, 16, 64));
            pmax = fmaxf(pmax, __shfl_xor(pmax, 32, 64));
            const float mnew = fmaxf(mrun, pmax);
            const float corr = ex2(mrun - mnew);  // log2-space rescale
            mrun = mnew;
            float rsum = 0.f;
#pragma unroll
            for (int nt = 0; nt < 4; ++nt)
#pragma unroll
                for (int r = 0; r < 4; ++r) {
                    const float e = ex2(p[nt][r] - mnew);  // scores in log2 units
                    p[nt][r] = e;
                    rsum += e;
                }
            rsum += __shfl_xor(rsum, 16, 64);
            rsum += __shfl_xor(rsum, 32, 64);
            lrun = lrun * corr + rsum;
#pragma unroll
            for (int dt = 0; dt < 4; ++dt)
#pragma unroll
                for (int e = 0; e < 4; ++e) oacc[dt][e] *= corr;

            // P[q][key] -> per-wave LDS: 2 packed cvt + one b64 write per nt
#pragma unroll
            for (int nt = 0; nt < 4; ++nt) {
                uint2v w;
                w[0] = pk2(p[nt][0], p[nt][1]);
                w[1] = pk2(p[nt][2], p[nt][3]);
                *(uint2v*)(Pw + fr * 72 + nt * 16 + r0) = w;
            }

            // O^T += V^T P^T
            __builtin_amdgcn_s_setprio(1);
#pragma unroll
            for (int kc = 0; kc < 2; ++kc) {
                const short8 pf = *(const short8*)(Pw + fr * 72 + kc * 32 + fk);
#pragma unroll
                for (int dt = 0; dt < 4; ++dt) {
                    const short8 vf = *(const short8*)(Vs + (dt * 16 + fr) * 72 + kc * 32 + fk);
                    oacc[dt] = __builtin_amdgcn_mfma_f32_16x16x32_bf16(vf, pf, oacc[dt], 0, 0, 0);
                }
            }
            __builtin_amdgcn_s_setprio(0);
        }
        __syncthreads();  // buf[cur^1] writes visible; buf[cur] reads done
    }

    if (split) {
        // partial epilogue: U^T bf16 [64 d][64 q] + per-row m,l (f32)
        const int pidx = (bh * 16 + (qs - 16)) * 2 + chunk;
        short* Up = Ub + pidx * 4096;
#pragma unroll
        for (int dt = 0; dt < 4; ++dt)
#pragma unroll
            for (int r = 0; r < 4; ++r)
                Up[(dt * 16 + r0 + r) * 64 + wave * 16 + fr] = bf16s(oacc[dt][r]);
        if (lane < 16) {
            Mb[pidx * 64 + wave * 16 + lane] = mrun;
            Lb[pidx * 64 + wave * 16 + lane] = lrun;
        }
        return;
    }

    // direct epilogue: transpose O^T back via LDS (Ps reused) and store
    short* Os = &Ps[0][0];
    const float iv = 1.0f / lrun;
#pragma unroll
    for (int dt = 0; dt < 4; ++dt) {
        uint2v w;
        w[0] = pk2(oacc[dt][0] * iv, oacc[dt][1] * iv);
        w[1] = pk2(oacc[dt][2] * iv, oacc[dt][3] * iv);
        *(uint2v*)(Os + (wave * 16 + fr) * 72 + dt * 16 + r0) = w;
    }
    __syncthreads();
    {
        const int row = t >> 2, c0 = (t & 3) * 16;
        const short8 o0 = *(const short8*)(Os + row * 72 + c0);
        const short8 o1 = *(const short8*)(Os + row * 72 + c0 + 8);
        short* Og = O + (long)(b * SEQ + q0 + row) * EMB + h * HDD + c0;
        *(short8*)Og = o0;
        *(short8*)(Og + 8) = o1;
    }
}

// ---- split-K merge (r17/r19-proven, unchanged) ----
__global__ __launch_bounds__(256) void k_merge(
        const short* __restrict__ Ub, const float* __restrict__ Mb,
        const float* __restrict__ Lb, short* __restrict__ O) {
    __shared__ float aS[64], bS[64], iL[64];
    __shared__ short tile[64 * 72];
    const int bid = blockIdx.x;
    const int bh = bid >> 4, sidx = bid & 15;
    const int h = bh % NHEAD, b = bh / NHEAD;
    const int q0 = (16 + sidx) * 64;
    const int p0 = (bh * 16 + sidx) * 2, p1 = p0 + 1;
    const int t = threadIdx.x;
    if (t < 64) {
        const float m1 = Mb[p0 * 64 + t], m2 = Mb[p1 * 64 + t];
        const float l1 = Lb[p0 * 64 + t], l2 = Lb[p1 * 64 + t];
        const float m = fmaxf(m1, m2);
        const float a = ex2(m1 - m), bb = ex2(m2 - m);
        aS[t] = a;
        bS[t] = bb;
        iL[t] = 1.0f / (l1 * a + l2 * bb);
    }
    __syncthreads();
    {
        const int d = t >> 2, qg = (t & 3) * 16;
        const short8 u1a = *(const short8*)(Ub + p0 * 4096 + d * 64 + qg);
        const short8 u1b = *(const short8*)(Ub + p0 * 4096 + d * 64 + qg + 8);
        const short8 u2a = *(const short8*)(Ub + p1 * 4096 + d * 64 + qg);
        const short8 u2b = *(const short8*)(Ub + p1 * 4096 + d * 64 + qg + 8);
#pragma unroll
        for (int i = 0; i < 8; ++i) {
            const int q = qg + i;
            tile[q * 72 + d] = bf16s((bf2f(u1a[i]) * aS[q] + bf2f(u2a[i]) * bS[q]) * iL[q]);
        }
#pragma unroll
        for (int i = 0; i < 8; ++i) {
            const int q = qg + 8 + i;
            tile[q * 72 + d] = bf16s((bf2f(u1b[i]) * aS[q] + bf2f(u2b[i]) * bS[q]) * iL[q]);
        }
    }
    __syncthreads();
    {
        const int q = t >> 2, dg = (t & 3) * 16;
        const short8 o0 = *(const short8*)(tile + q * 72 + dg);
        const short8 o1 = *(const short8*)(tile + q * 72 + dg + 8);
        short* Og = O + (long)(b * SEQ + q0 + q) * EMB + h * HDD + dg;
        *(short8*)Og = o0;
        *(short8*)(Og + 8) = o1;
    }
}

extern "C" void kernel_launch(void* const* d_in, const int* in_sizes, int n_in,
                              void* d_out, int out_size, void* d_ws, size_t ws_size,
                              hipStream_t stream) {
    const float* x  = (const float*)d_in[0];
    const float* Wq = (const float*)d_in[1];
    const float* Wk = (const float*)d_in[2];
    const float* Wv = (const float*)d_in[3];
    const float* Wo = (const float*)d_in[4];
    const float* bo = (const float*)d_in[5];
    float* out = (float*)d_out;

    char* ws = (char*)d_ws;
    short* xb  = (short*)(ws + 0);         // 4096x768 bf16 (dead after gemm0)
    short* WqT = (short*)(ws + 6291456);   // (dead after gemm0)
    short* WkT = (short*)(ws + 7471104);
    short* WvT = (short*)(ws + 8650752);
    short* WoT = (short*)(ws + 9830400);
    short* Qb  = (short*)(ws + 11010048);  // [2,12,2048,64] bf16 (pre-scaled, log2-space)
    short* Kb  = (short*)(ws + 17301504);  // [2,12,2048,64]
    short* VTb = (short*)(ws + 23592960);  // [2,12,64,2048] (transposed)
    short* Ob  = (short*)(ws + 29884416);  // [4096,768] bf16
    // split-K partials overlay the dead xb/WqT regions during attn+merge:
    short* Ub  = (short*)(ws + 0);         // 768 x [64][64] bf16
    float* Mb  = (float*)(ws + 6291456);   // 768 x 64 f32
    float* Lb  = (float*)(ws + 6488064);   // 768 x 64 f32

    k_cvt_all<<<dim3(2112), dim3(256), 0, stream>>>(
        x, Wq, Wk, Wv, Wo, xb, WqT, WkT, WvT, WoT);
    k_gemm<0><<<dim3(6, 32, 3), dim3(256), 0, stream>>>(
        xb, WqT, WkT, WvT, Qb, Kb, VTb, (const float*)nullptr, (float*)nullptr);
    k_attn<<<dim3(24, 48), dim3(256), 0, stream>>>(Qb, Kb, VTb, Ob, Ub, Mb, Lb);
    k_merge<<<dim3(384), dim3(256), 0, stream>>>(Ub, Mb, Lb, Ob);
    k_gemm<1><<<dim3(6, 32, 1), dim3(256), 0, stream>>>(
        Ob, WoT, (const short*)nullptr, (const short*)nullptr,
        (short*)nullptr, (short*)nullptr, (short*)nullptr, bo, out);
}